// Round 2
// baseline (3744.799 us; speedup 1.0000x reference)
//
#include <hip/hip_runtime.h>
#include <hip/hip_bf16.h>
#include <math.h>

// Problem constants (SelectiveSSM: D_MODEL=1024, D_STATE=16, D_CONV=4, EXPAND=2)
#define B_SZ 4
#define T_SZ 2048
#define DM   1024
#define DI   2048      // D_INNER
#define DS   16        // D_STATE
#define BT   (B_SZ*T_SZ)   // 8192

__device__ __forceinline__ float siluf(float v) {
    return v / (1.f + __expf(-v));
}
__device__ __forceinline__ float softplusf(float x) {
    // stable: max(x,0) + log1p(exp(-|x|))  == jax.nn.softplus
    return fmaxf(x, 0.f) + log1pf(__expf(-fabsf(x)));
}

// ---------------------------------------------------------------------------
// Generic fp32 tiled GEMM:  C[m,n] = sum_k A[m,k] * B[n,k]  (A: MxK, B: NxK,
// both row-major / K-contiguous — "NT" layout, matches all einsums here).
// Split store: cols [0,nsplit) -> out0 (ldc=nsplit), cols [nsplit,N) -> out1.
// act: 0 = none, 1 = softplus. bias (length N) optional.
// ---------------------------------------------------------------------------
#define BM 64
#define BN 64
#define BK 16

__global__ __launch_bounds__(256)
void gemm_nt(const float* __restrict__ A, const float* __restrict__ Bm,
             const float* __restrict__ bias,
             float* __restrict__ out0, float* __restrict__ out1,
             int M, int N, int K, int nsplit, int act)
{
    __shared__ float As[BK][BM + 4];
    __shared__ float Bs[BK][BN + 4];
    const int tid = threadIdx.x;
    const int bm = blockIdx.y * BM;
    const int bn = blockIdx.x * BN;
    const int tx = tid & 15;       // micro-tile col group
    const int ty = tid >> 4;       // micro-tile row group
    const int lr = tid >> 2;       // load row 0..63
    const int lc = (tid & 3) * 4;  // load col offset 0,4,8,12

    float acc[4][4];
#pragma unroll
    for (int i = 0; i < 4; i++)
#pragma unroll
        for (int j = 0; j < 4; j++) acc[i][j] = 0.f;

    for (int k0 = 0; k0 < K; k0 += BK) {
        float4 av = *(const float4*)(A + (size_t)(bm + lr) * K + k0 + lc);
        float4 bv = make_float4(0.f, 0.f, 0.f, 0.f);
        if (bn + lr < N)
            bv = *(const float4*)(Bm + (size_t)(bn + lr) * K + k0 + lc);
        As[lc + 0][lr] = av.x; As[lc + 1][lr] = av.y;
        As[lc + 2][lr] = av.z; As[lc + 3][lr] = av.w;
        Bs[lc + 0][lr] = bv.x; Bs[lc + 1][lr] = bv.y;
        Bs[lc + 2][lr] = bv.z; Bs[lc + 3][lr] = bv.w;
        __syncthreads();
#pragma unroll
        for (int k = 0; k < BK; k++) {
            float4 a = *(const float4*)&As[k][ty * 4];
            float4 b = *(const float4*)&Bs[k][tx * 4];
            float ar[4] = {a.x, a.y, a.z, a.w};
            float br[4] = {b.x, b.y, b.z, b.w};
#pragma unroll
            for (int i = 0; i < 4; i++)
#pragma unroll
                for (int j = 0; j < 4; j++)
                    acc[i][j] = fmaf(ar[i], br[j], acc[i][j]);
        }
        __syncthreads();
    }

    const int ldc1 = N - nsplit;
#pragma unroll
    for (int i = 0; i < 4; i++) {
        const int row = bm + ty * 4 + i;
#pragma unroll
        for (int j = 0; j < 4; j++) {
            const int col = bn + tx * 4 + j;
            if (col >= N) continue;
            float v = acc[i][j];
            if (bias) v += bias[col];
            if (act == 1) v = softplusf(v);
            if (col < nsplit) out0[(size_t)row * nsplit + col] = v;
            else              out1[(size_t)row * ldc1 + (col - nsplit)] = v;
        }
    }
}

// ---------------------------------------------------------------------------
// Depthwise causal conv (width 4) + SiLU.  xc[b,t,i] = silu(sum_k xp[b,t-3+k,i]
// * cw[i,k] + cb[i]).  One thread per (b,t,i).
// ---------------------------------------------------------------------------
__global__ __launch_bounds__(256)
void conv_silu(const float* __restrict__ xp, const float* __restrict__ cw,
               const float* __restrict__ cb, float* __restrict__ xc)
{
    const int idx = blockIdx.x * 256 + threadIdx.x;   // over BT*DI = 16.7M
    const int i  = idx & (DI - 1);
    const int bt = idx >> 11;                         // DI = 2^11
    const int t  = bt & (T_SZ - 1);
    float acc = cb[i];
    float4 w = *(const float4*)(cw + (size_t)i * 4);
    float wr[4] = {w.x, w.y, w.z, w.w};
#pragma unroll
    for (int k = 0; k < 4; k++) {
        const int tt = t - 3 + k;
        if (tt >= 0)
            acc = fmaf(xp[(size_t)(bt - 3 + k) * DI + i], wr[k], acc);
    }
    xc[idx] = siluf(acc);
}

// ---------------------------------------------------------------------------
// Sequential selective scan. One thread per (b,d); h[16] fp32 states in regs.
// Writes y IN-PLACE over dts (same (b,t,d) element): safe because each thread
// owns one (b,d) column exclusively and the t+1 prefetch read happens before
// the t write.
// ---------------------------------------------------------------------------
__global__ __launch_bounds__(256)
void scan_kernel(const float* __restrict__ xc, const float* __restrict__ dts,
                 const float* __restrict__ Bp, const float* __restrict__ Cp,
                 const float* __restrict__ A_log, float* __restrict__ y)
{
    const int d = blockIdx.x * 256 + threadIdx.x;   // 0..DI-1
    const int b = blockIdx.y;
    float A[DS];
#pragma unroll
    for (int s = 0; s < DS; s++) A[s] = -__expf(A_log[s]);
    float h[DS];
#pragma unroll
    for (int s = 0; s < DS; s++) h[s] = 0.f;

    const float*  xcb = xc  + (size_t)b * T_SZ * DI + d;
    const float*  dtb = dts + (size_t)b * T_SZ * DI + d;
    const float4* Bb  = (const float4*)(Bp + (size_t)b * T_SZ * DS);
    const float4* Cb  = (const float4*)(Cp + (size_t)b * T_SZ * DS);
    float*        yb  = y   + (size_t)b * T_SZ * DI + d;

    float xv = xcb[0];
    float dv = dtb[0];
    float4 Bv[4] = {Bb[0], Bb[1], Bb[2], Bb[3]};
    float4 Cv[4] = {Cb[0], Cb[1], Cb[2], Cb[3]};

    for (int t = 0; t < T_SZ; t++) {
        float xn = 0.f, dn = 0.f;
        float4 Bn[4], Cn[4];
        if (t + 1 < T_SZ) {
            xn = xcb[(size_t)(t + 1) * DI];
            dn = dtb[(size_t)(t + 1) * DI];
#pragma unroll
            for (int q = 0; q < 4; q++) {
                Bn[q] = Bb[(t + 1) * 4 + q];
                Cn[q] = Cb[(t + 1) * 4 + q];
            }
        } else {
#pragma unroll
            for (int q = 0; q < 4; q++) {
                Bn[q] = make_float4(0.f, 0.f, 0.f, 0.f);
                Cn[q] = make_float4(0.f, 0.f, 0.f, 0.f);
            }
        }
        const float* bs = (const float*)&Bv[0];
        const float* cs = (const float*)&Cv[0];
        const float dx = dv * xv;
        float acc = 0.f;
#pragma unroll
        for (int s = 0; s < DS; s++) {
            float dA = __expf(dv * A[s]);
            h[s] = fmaf(dA, h[s], dx * bs[s]);
            acc = fmaf(h[s], cs[s], acc);
        }
        yb[(size_t)t * DI] = acc;   // overwrites dts[t] — already consumed
        xv = xn; dv = dn;
#pragma unroll
        for (int q = 0; q < 4; q++) { Bv[q] = Bn[q]; Cv[q] = Cn[q]; }
    }
}

// ---------------------------------------------------------------------------
// Fused LayerNorm(d) + residual (xc*D) + gate (silu(z)).  In-place on y.
// One block per (b,t) row; 256 threads x 8 elements.
// ---------------------------------------------------------------------------
__global__ __launch_bounds__(256)
void ln_fuse(float* __restrict__ y, const float* __restrict__ xc,
             const float* __restrict__ z, const float* __restrict__ g,
             const float* __restrict__ bln, const float* __restrict__ Dp)
{
    __shared__ float rs[256], rss[256];
    const int bt  = blockIdx.x;
    const int tid = threadIdx.x;
    float*       yr = y  + (size_t)bt * DI;
    const float* xr = xc + (size_t)bt * DI;
    const float* zr = z  + (size_t)bt * DI;

    float v[8];
    float s = 0.f, ss = 0.f;
#pragma unroll
    for (int j = 0; j < 8; j++) {
        v[j] = yr[tid + j * 256];
        s  += v[j];
        ss += v[j] * v[j];
    }
    rs[tid] = s; rss[tid] = ss;
    __syncthreads();
    for (int off = 128; off > 0; off >>= 1) {
        if (tid < off) { rs[tid] += rs[tid + off]; rss[tid] += rss[tid + off]; }
        __syncthreads();
    }
    const float mu   = rs[0] * (1.f / DI);
    const float var  = rss[0] * (1.f / DI) - mu * mu;
    const float rstd = rsqrtf(var + 1e-5f);
#pragma unroll
    for (int j = 0; j < 8; j++) {
        const int dcol = tid + j * 256;
        float yn = (v[j] - mu) * rstd * g[dcol] + bln[dcol];
        yn += xr[dcol] * Dp[dcol];
        yn *= siluf(zr[dcol]);
        yr[dcol] = yn;
    }
}

// ---------------------------------------------------------------------------
// Workspace layout (fits in < 194 MiB; previous round overflowed 256 MiB):
//   buf0 [SZ]: xp (gemm1) -> dead after conv -> dts (gemm3) -> y (scan,
//              in-place) -> ln_fuse in-place -> gemm7 input
//   buf1 [SZ]: z   (live until ln_fuse)
//   buf2 [SZ]: xc  (live until ln_fuse)
//   tail     : Bp, Cp (BT*DS floats each = 0.5 MiB each)
// ---------------------------------------------------------------------------
extern "C" void kernel_launch(void* const* d_in, const int* in_sizes, int n_in,
                              void* d_out, int out_size, void* d_ws, size_t ws_size,
                              hipStream_t stream)
{
    const float* x      = (const float*)d_in[0];
    const float* W_in   = (const float*)d_in[1];
    const float* conv_w = (const float*)d_in[2];
    const float* conv_b = (const float*)d_in[3];
    const float* W_x    = (const float*)d_in[4];
    const float* W_dt   = (const float*)d_in[5];
    const float* b_dt   = (const float*)d_in[6];
    const float* A_log  = (const float*)d_in[7];
    const float* D_par  = (const float*)d_in[8];
    const float* W_out  = (const float*)d_in[9];
    const float* ln_g   = (const float*)d_in[10];
    const float* ln_b   = (const float*)d_in[11];
    float* out = (float*)d_out;

    float* ws = (float*)d_ws;
    const size_t SZ = (size_t)BT * DI;   // 16.78M floats per (B,T,DI) buffer
    float* buf0 = ws;                    // xp -> dts -> y
    float* z    = ws + SZ;
    float* xc   = ws + 2 * SZ;
    float* Bp   = ws + 3 * SZ;           // (BT,16)
    float* Cp   = Bp + (size_t)BT * DS;  // (BT,16)

    float* xp  = buf0;
    float* dts = buf0;
    float* y   = buf0;

    dim3 blk(256);

    // 1) xz = x @ W_in^T, split into xp | z
    gemm_nt<<<dim3((2 * DI) / BN, BT / BM), blk, 0, stream>>>(
        x, W_in, nullptr, xp, z, BT, 2 * DI, DM, DI, 0);

    // 2) depthwise causal conv + silu  (xp -> xc; xp dead afterwards)
    conv_silu<<<dim3((BT * DI) / 256), blk, 0, stream>>>(xp, conv_w, conv_b, xc);

    // 3) dt = softplus(xc @ W_dt^T + b_dt)  -> reuse buf0
    gemm_nt<<<dim3(DI / BN, BT / BM), blk, 0, stream>>>(
        xc, W_dt, b_dt, dts, nullptr, BT, DI, DI, DI, 1);

    // 4) ssm = xc @ W_x^T, split into Bp | Cp  (N=32)
    gemm_nt<<<dim3(1, BT / BM), blk, 0, stream>>>(
        xc, W_x, nullptr, Bp, Cp, BT, 2 * DS, DI, DS, 0);

    // 5) selective scan -> y (in-place over dts)
    scan_kernel<<<dim3(DI / 256, B_SZ), blk, 0, stream>>>(
        xc, dts, Bp, Cp, A_log, y);

    // 6) LayerNorm + xc*D + silu(z) gate (in place on y)
    ln_fuse<<<dim3(BT), blk, 0, stream>>>(y, xc, z, ln_g, ln_b, D_par);

    // 7) out = y @ W_out^T
    gemm_nt<<<dim3(DM / BN, BT / BM), blk, 0, stream>>>(
        y, W_out, nullptr, out, nullptr, BT, DM, DI, DM, 0);
}

// Round 3
// 796.302 us; speedup vs baseline: 4.7027x; 4.7027x over previous
//
#include <hip/hip_runtime.h>
#include <hip/hip_bf16.h>
#include <math.h>
#include <stdint.h>

// Problem constants (SelectiveSSM: D_MODEL=1024, D_STATE=16, D_CONV=4, EXPAND=2)
#define B_SZ 4
#define T_SZ 2048
#define DM   1024
#define DI   2048          // D_INNER
#define DS   16            // D_STATE
#define BT   (B_SZ*T_SZ)   // 8192
#define NC   2176          // padded N for fused dt+ssm GEMM (17 x 128)

typedef __attribute__((ext_vector_type(8))) short short8;
typedef __attribute__((ext_vector_type(4))) float f32x4;

__device__ __forceinline__ float siluf(float v) { return v / (1.f + __expf(-v)); }
__device__ __forceinline__ float softplusf(float x) {
    return fmaxf(x, 0.f) + log1pf(__expf(-fabsf(x)));
}
__device__ __forceinline__ unsigned short f2b(float f) {
    __hip_bfloat16 h = __float2bfloat16(f);
    return *reinterpret_cast<unsigned short*>(&h);
}
__device__ __forceinline__ float b2f(unsigned short u) {
    unsigned v = (unsigned)u << 16;
    float f;
    __builtin_memcpy(&f, &v, 4);
    return f;
}
__device__ __forceinline__ void gld_lds16(const void* g, void* l) {
    __builtin_amdgcn_global_load_lds(
        (const __attribute__((address_space(1))) unsigned int*)g,
        (__attribute__((address_space(3))) unsigned int*)l,
        16, 0, 0);
}

// ---------------------------------------------------------------------------
// fp32 -> bf16 conversion (vectorized x4)
// ---------------------------------------------------------------------------
__global__ __launch_bounds__(256)
void cvt_bf16(const float* __restrict__ src, unsigned short* __restrict__ dst, int n4)
{
    int i = blockIdx.x * 256 + threadIdx.x;
    if (i >= n4) return;
    float4 v = ((const float4*)src)[i];
    ushort4 o;
    o.x = f2b(v.x); o.y = f2b(v.y); o.z = f2b(v.z); o.w = f2b(v.w);
    ((ushort4*)dst)[i] = o;
}

// Pack W_dt (2048xK) + W_x (32xK) + zero pad into Wcb (2176xK) bf16
__global__ __launch_bounds__(256)
void cvt_wc(const float* __restrict__ Wdt, const float* __restrict__ Wx,
            unsigned short* __restrict__ dst)
{
    const int n4 = NC * (DI / 4);          // 2176*512
    int i = blockIdx.x * 256 + threadIdx.x;
    if (i >= n4) return;
    int row = i >> 9;                      // / (2048/4)
    int c4  = i & 511;
    float4 v;
    if (row < 2048)      v = ((const float4*)Wdt)[(size_t)row * 512 + c4];
    else if (row < 2080) v = ((const float4*)Wx)[(size_t)(row - 2048) * 512 + c4];
    else                 v = make_float4(0.f, 0.f, 0.f, 0.f);
    ushort4 o;
    o.x = f2b(v.x); o.y = f2b(v.y); o.z = f2b(v.z); o.w = f2b(v.w);
    ((ushort4*)dst)[i] = o;
}

// ---------------------------------------------------------------------------
// bf16 MFMA GEMM (m97 structure): C[m,n] = sum_k A[m,k]*B[n,k], A: MxK bf16,
// B: NxK bf16, both row-major. 128x128 tile, BK=32, 4 waves (2x2), each wave
// 4x4 grid of 16x16x32 MFMA. global_load_lds width-16 staging.
// mode 0: bf16 split store  cols<2048 -> o0, else -> o1 (both ldc 2048)
// mode 1: cols<2048 -> softplus(v+bias[col]) fp32 o0 (ldc 2048);
//         2048..2063 -> o1[row*16+c]; 2064..2079 -> o2[row*16+c]; >=2080 drop
// mode 2: fp32 plain store to o0, ldc = N
// ---------------------------------------------------------------------------
__global__ __launch_bounds__(256)
void gemm_mfma(const unsigned short* __restrict__ A,
               const unsigned short* __restrict__ Bm,
               int M, int N, int K, int mode,
               const float* __restrict__ bias,
               void* __restrict__ o0, void* __restrict__ o1, void* __restrict__ o2)
{
    __shared__ unsigned short As[128 * 32];   // 8 KB
    __shared__ unsigned short Bs[128 * 32];   // 8 KB
    const int tid  = threadIdx.x;
    const int bm   = blockIdx.y * 128;
    const int bn   = blockIdx.x * 128;
    const int lane = tid & 63;
    const int wave = tid >> 6;
    const int wm   = (wave >> 1) * 64;
    const int wn   = (wave & 1) * 64;

    f32x4 zero4 = {0.f, 0.f, 0.f, 0.f};
    f32x4 acc[4][4];
#pragma unroll
    for (int i = 0; i < 4; i++)
#pragma unroll
        for (int j = 0; j < 4; j++) acc[i][j] = zero4;

    // staging: thread -> 16B (8 bf16). row = tid/4 (0..63), col = (tid%4)*8
    const int sr = tid >> 2;
    const int sc = (tid & 3) * 8;
    const unsigned short* Ag = A  + (size_t)(bm + sr) * K + sc;
    const unsigned short* Bg = Bm + (size_t)(bn + sr) * K + sc;

    const int fr = lane & 15;          // row within 16-tile
    const int fk = (lane >> 4) * 8;    // k offset within 32

    for (int k0 = 0; k0 < K; k0 += 32) {
        gld_lds16(Ag + k0,                    &As[tid * 8]);
        gld_lds16(Ag + (size_t)64 * K + k0,   &As[2048 + tid * 8]);
        gld_lds16(Bg + k0,                    &Bs[tid * 8]);
        gld_lds16(Bg + (size_t)64 * K + k0,   &Bs[2048 + tid * 8]);
        __syncthreads();
        short8 af[4], bf[4];
#pragma unroll
        for (int i = 0; i < 4; i++) {
            af[i] = *(const short8*)&As[(wm + i * 16 + fr) * 32 + fk];
            bf[i] = *(const short8*)&Bs[(wn + i * 16 + fr) * 32 + fk];
        }
#pragma unroll
        for (int i = 0; i < 4; i++)
#pragma unroll
            for (int j = 0; j < 4; j++)
                acc[i][j] = __builtin_amdgcn_mfma_f32_16x16x32_bf16(
                    af[i], bf[j], acc[i][j], 0, 0, 0);
        __syncthreads();
    }

    // epilogue. C/D layout: col = lane&15, row = (lane>>4)*4 + r  [m89/m91]
    const int cr0 = bm + wm + (lane >> 4) * 4;
    const int cc0 = bn + wn + (lane & 15);
#pragma unroll
    for (int i = 0; i < 4; i++) {
#pragma unroll
        for (int j = 0; j < 4; j++) {
            const int col = cc0 + j * 16;
#pragma unroll
            for (int r = 0; r < 4; r++) {
                const int row = cr0 + i * 16 + r;
                float v = acc[i][j][r];
                if (mode == 0) {
                    if (col < 2048)
                        ((unsigned short*)o0)[(size_t)row * 2048 + col] = f2b(v);
                    else
                        ((unsigned short*)o1)[(size_t)row * 2048 + col - 2048] = f2b(v);
                } else if (mode == 1) {
                    if (col < 2048) {
                        ((float*)o0)[(size_t)row * 2048 + col] = softplusf(v + bias[col]);
                    } else if (col < 2064) {
                        ((float*)o1)[(size_t)row * DS + (col - 2048)] = v;
                    } else if (col < 2080) {
                        ((float*)o2)[(size_t)row * DS + (col - 2064)] = v;
                    }
                } else {
                    ((float*)o0)[(size_t)row * N + col] = v;
                }
            }
        }
    }
}

// ---------------------------------------------------------------------------
// Depthwise causal conv (width 4) + SiLU, bf16 in -> bf16 out.
// ---------------------------------------------------------------------------
__global__ __launch_bounds__(256)
void conv_silu(const unsigned short* __restrict__ xpb, const float* __restrict__ cw,
               const float* __restrict__ cb, unsigned short* __restrict__ xcb)
{
    const int idx = blockIdx.x * 256 + threadIdx.x;   // over BT*DI
    const int i  = idx & (DI - 1);
    const int bt = idx >> 11;
    const int t  = bt & (T_SZ - 1);
    float acc = cb[i];
    float4 w = *(const float4*)(cw + (size_t)i * 4);
    float wr[4] = {w.x, w.y, w.z, w.w};
#pragma unroll
    for (int k = 0; k < 4; k++) {
        const int tt = t - 3 + k;
        if (tt >= 0)
            acc = fmaf(b2f(xpb[(size_t)(bt - 3 + k) * DI + i]), wr[k], acc);
    }
    xcb[idx] = f2b(siluf(acc));
}

// ---------------------------------------------------------------------------
// Chunked parallel selective scan. Block: 16 chunks x 16 d-cols = 256 thr.
// Grid: (DI/16, B). Phase1: per-chunk (h_end, prod dA) from h0=0.
// Phase2: LDS carry combine (16 cols x 16 states in parallel).
// Phase3: replay with corrected h0, write y fp32 in-place over dts.
// ---------------------------------------------------------------------------
#define CH 16
#define CL (T_SZ / CH)   // 128

__global__ __launch_bounds__(256)
void scan2(const unsigned short* __restrict__ xcb, float* __restrict__ dty,
           const float* __restrict__ Bp, const float* __restrict__ Cp,
           const float* __restrict__ A_log)
{
    __shared__ float shH[CH][16][DS];
    __shared__ float shP[CH][16][DS];
    __shared__ float shI[CH][16][DS];
    const int tid = threadIdx.x;
    const int c = tid >> 4;
    const int g = tid & 15;
    const int b = blockIdx.y;
    const int d = blockIdx.x * 16 + g;

    float A[DS];
#pragma unroll
    for (int s = 0; s < DS; s++) A[s] = -__expf(A_log[s]);

    const size_t colbase = (size_t)b * T_SZ * DI + d;
    const unsigned short* xp = xcb + colbase + (size_t)c * CL * DI;
    float* dp = dty + colbase + (size_t)c * CL * DI;
    const float4* Bb = (const float4*)(Bp + ((size_t)b * T_SZ + c * CL) * DS);
    const float4* Cb = (const float4*)(Cp + ((size_t)b * T_SZ + c * CL) * DS);

    float h[DS], P[DS];
#pragma unroll
    for (int s = 0; s < DS; s++) { h[s] = 0.f; P[s] = 1.f; }

    // phase 1: local scan, track decay product; no y needed
    for (int i = 0; i < CL; i++) {
        const float xv = b2f(xp[(size_t)i * DI]);
        const float dv = dp[(size_t)i * DI];
        float4 Bv[4] = {Bb[i*4+0], Bb[i*4+1], Bb[i*4+2], Bb[i*4+3]};
        const float* bs = (const float*)&Bv[0];
        const float dx = dv * xv;
#pragma unroll
        for (int s = 0; s < DS; s++) {
            const float dA = __expf(dv * A[s]);
            h[s] = fmaf(dA, h[s], dx * bs[s]);
            P[s] *= dA;
        }
    }
#pragma unroll
    for (int s = 0; s < DS; s += 4) {
        *(float4*)&shH[c][g][s] = make_float4(h[s], h[s+1], h[s+2], h[s+3]);
        *(float4*)&shP[c][g][s] = make_float4(P[s], P[s+1], P[s+2], P[s+3]);
    }
    __syncthreads();

    // phase 2: carry combine — remap threads to (g2, s2)
    {
        const int g2 = tid >> 4, s2 = tid & 15;
        float hin = 0.f;
        shI[0][g2][s2] = 0.f;
        for (int cc = 1; cc < CH; cc++) {
            hin = fmaf(shP[cc-1][g2][s2], hin, shH[cc-1][g2][s2]);
            shI[cc][g2][s2] = hin;
        }
    }
    __syncthreads();

    // phase 3: replay with corrected init, emit y (in-place over dts)
#pragma unroll
    for (int s = 0; s < DS; s++) h[s] = shI[c][g][s];
    for (int i = 0; i < CL; i++) {
        const float xv = b2f(xp[(size_t)i * DI]);
        const float dv = dp[(size_t)i * DI];
        float4 Bv[4] = {Bb[i*4+0], Bb[i*4+1], Bb[i*4+2], Bb[i*4+3]};
        float4 Cv[4] = {Cb[i*4+0], Cb[i*4+1], Cb[i*4+2], Cb[i*4+3]};
        const float* bs = (const float*)&Bv[0];
        const float* cs = (const float*)&Cv[0];
        const float dx = dv * xv;
        float yv = 0.f;
#pragma unroll
        for (int s = 0; s < DS; s++) {
            const float dA = __expf(dv * A[s]);
            h[s] = fmaf(dA, h[s], dx * bs[s]);
            yv = fmaf(h[s], cs[s], yv);
        }
        dp[(size_t)i * DI] = yv;   // overwrites dt[t] after its last use
    }
}

// ---------------------------------------------------------------------------
// Fused LayerNorm + xc*D residual + silu(z) gate. y fp32 in, yb bf16 out.
// ---------------------------------------------------------------------------
__global__ __launch_bounds__(256)
void ln_fuse(const float* __restrict__ y, const unsigned short* __restrict__ xcb,
             const unsigned short* __restrict__ zb, const float* __restrict__ g,
             const float* __restrict__ bln, const float* __restrict__ Dp,
             unsigned short* __restrict__ yb)
{
    __shared__ float rs[256], rss[256];
    const int bt  = blockIdx.x;
    const int tid = threadIdx.x;
    const float* yr = y + (size_t)bt * DI;
    const unsigned short* xr = xcb + (size_t)bt * DI;
    const unsigned short* zr = zb + (size_t)bt * DI;
    unsigned short* orow = yb + (size_t)bt * DI;

    float v[8];
    float s = 0.f, ss = 0.f;
#pragma unroll
    for (int j = 0; j < 8; j++) {
        v[j] = yr[tid + j * 256];
        s  += v[j];
        ss += v[j] * v[j];
    }
    rs[tid] = s; rss[tid] = ss;
    __syncthreads();
    for (int off = 128; off > 0; off >>= 1) {
        if (tid < off) { rs[tid] += rs[tid + off]; rss[tid] += rss[tid + off]; }
        __syncthreads();
    }
    const float mu   = rs[0] * (1.f / DI);
    const float var  = rss[0] * (1.f / DI) - mu * mu;
    const float rstd = rsqrtf(var + 1e-5f);
#pragma unroll
    for (int j = 0; j < 8; j++) {
        const int dcol = tid + j * 256;
        float yn = (v[j] - mu) * rstd * g[dcol] + bln[dcol];
        yn += b2f(xr[dcol]) * Dp[dcol];
        yn *= siluf(b2f(zr[dcol]));
        orow[dcol] = f2b(yn);
    }
}

// ---------------------------------------------------------------------------
// Workspace layout (MiB offsets, total ~175 MiB):
//   [  0, 32)  xpb bf16  (G1 out) -> dead after conv -> yb bf16 (ln out)
//   [ 32, 64)  zb  bf16
//   [ 64, 96)  xcb bf16
//   [ 96,160)  dts fp32 (G3 out) -> y fp32 (scan, in-place)
//       [ 96,112) xb bf16   (dead before G3 writes dts)
//       [112,120) W_inb bf16 (dead before G3)
//   [160,169)  Wcb bf16 (2176x2048: W_dt | W_x | zeros)
//   [169,173)  W_outb bf16
//   [174,175)  Bp, Cp fp32
// ---------------------------------------------------------------------------
extern "C" void kernel_launch(void* const* d_in, const int* in_sizes, int n_in,
                              void* d_out, int out_size, void* d_ws, size_t ws_size,
                              hipStream_t stream)
{
    const float* x      = (const float*)d_in[0];
    const float* W_in   = (const float*)d_in[1];
    const float* conv_w = (const float*)d_in[2];
    const float* conv_b = (const float*)d_in[3];
    const float* W_x    = (const float*)d_in[4];
    const float* W_dt   = (const float*)d_in[5];
    const float* b_dt   = (const float*)d_in[6];
    const float* A_log  = (const float*)d_in[7];
    const float* D_par  = (const float*)d_in[8];
    const float* W_out  = (const float*)d_in[9];
    const float* ln_g   = (const float*)d_in[10];
    const float* ln_b   = (const float*)d_in[11];
    float* out = (float*)d_out;

    char* w = (char*)d_ws;
    const size_t MB = 1ull << 20;
    unsigned short* xpb    = (unsigned short*)(w);
    unsigned short* zb     = (unsigned short*)(w + 32 * MB);
    unsigned short* xcb    = (unsigned short*)(w + 64 * MB);
    float*          dts    = (float*)(w + 96 * MB);
    unsigned short* xb     = (unsigned short*)(w + 96 * MB);
    unsigned short* W_inb  = (unsigned short*)(w + 112 * MB);
    unsigned short* Wcb    = (unsigned short*)(w + 160 * MB);
    unsigned short* W_outb = (unsigned short*)(w + 169 * MB);
    float*          BpF    = (float*)(w + 174 * MB);
    float*          CpF    = BpF + (size_t)BT * DS;
    unsigned short* yb     = xpb;   // reuse after conv

    dim3 blk(256);

    // conversions to bf16
    cvt_bf16<<<dim3((BT * DM / 4 + 255) / 256), blk, 0, stream>>>(x, xb, BT * DM / 4);
    cvt_bf16<<<dim3((2 * DI * DM / 4 + 255) / 256), blk, 0, stream>>>(W_in, W_inb, 2 * DI * DM / 4);
    cvt_wc<<<dim3((NC * DI / 4 + 255) / 256), blk, 0, stream>>>(W_dt, W_x, Wcb);
    cvt_bf16<<<dim3((DM * DI / 4 + 255) / 256), blk, 0, stream>>>(W_out, W_outb, DM * DI / 4);

    // 1) xz = x @ W_in^T -> split bf16 xpb | zb
    gemm_mfma<<<dim3(2 * DI / 128, BT / 128), blk, 0, stream>>>(
        xb, W_inb, BT, 2 * DI, DM, 0, nullptr, xpb, zb, nullptr);

    // 2) depthwise conv + silu -> xcb bf16
    conv_silu<<<dim3(BT * DI / 256), blk, 0, stream>>>(xpb, conv_w, conv_b, xcb);

    // 3) fused dt+ssm GEMM: [W_dt | W_x] -> dts fp32 (softplus+bias), Bp, Cp
    gemm_mfma<<<dim3(NC / 128, BT / 128), blk, 0, stream>>>(
        xcb, Wcb, BT, NC, DI, 1, b_dt, dts, BpF, CpF);

    // 4) chunked parallel scan -> y fp32 (in-place over dts)
    scan2<<<dim3(DI / 16, B_SZ), blk, 0, stream>>>(xcb, dts, BpF, CpF, A_log);

    // 5) LayerNorm + residual + gate -> yb bf16
    ln_fuse<<<dim3(BT), blk, 0, stream>>>(dts, xcb, zb, ln_g, ln_b, D_par, yb);

    // 6) out = y @ W_out^T -> fp32
    gemm_mfma<<<dim3(DM / 128, BT / 128), blk, 0, stream>>>(
        yb, W_outb, BT, DM, DI, 2, nullptr, out, nullptr, nullptr);
}

// Round 4
// 737.357 us; speedup vs baseline: 5.0787x; 1.0799x over previous
//
#include <hip/hip_runtime.h>
#include <hip/hip_bf16.h>
#include <math.h>
#include <stdint.h>

// Problem constants (SelectiveSSM: D_MODEL=1024, D_STATE=16, D_CONV=4, EXPAND=2)
#define B_SZ 4
#define T_SZ 2048
#define DM   1024
#define DI   2048          // D_INNER
#define DS   16            // D_STATE
#define BT   (B_SZ*T_SZ)   // 8192
#define NC   2176          // padded N for fused dt+ssm GEMM (17 x 128)

typedef __attribute__((ext_vector_type(8))) short short8;
typedef __attribute__((ext_vector_type(4))) float f32x4;

__device__ __forceinline__ float siluf(float v) { return v / (1.f + __expf(-v)); }
__device__ __forceinline__ float softplusf(float x) {
    return fmaxf(x, 0.f) + log1pf(__expf(-fabsf(x)));
}
__device__ __forceinline__ unsigned short f2b(float f) {
    __hip_bfloat16 h = __float2bfloat16(f);
    return *reinterpret_cast<unsigned short*>(&h);
}
__device__ __forceinline__ float b2f(unsigned short u) {
    unsigned v = (unsigned)u << 16;
    float f;
    __builtin_memcpy(&f, &v, 4);
    return f;
}
__device__ __forceinline__ void gld_lds16(const void* g, void* l) {
    __builtin_amdgcn_global_load_lds(
        (const __attribute__((address_space(1))) unsigned int*)g,
        (__attribute__((address_space(3))) unsigned int*)l,
        16, 0, 0);
}

// ---------------------------------------------------------------------------
// fp32 -> bf16 conversion (vectorized x4)
// ---------------------------------------------------------------------------
__global__ __launch_bounds__(256)
void cvt_bf16(const float* __restrict__ src, unsigned short* __restrict__ dst, int n4)
{
    int i = blockIdx.x * 256 + threadIdx.x;
    if (i >= n4) return;
    float4 v = ((const float4*)src)[i];
    ushort4 o;
    o.x = f2b(v.x); o.y = f2b(v.y); o.z = f2b(v.z); o.w = f2b(v.w);
    ((ushort4*)dst)[i] = o;
}

// Pack W_dt (2048xK) + W_x (32xK) + zero pad into Wcb (2176xK) bf16
__global__ __launch_bounds__(256)
void cvt_wc(const float* __restrict__ Wdt, const float* __restrict__ Wx,
            unsigned short* __restrict__ dst)
{
    const int n4 = NC * (DI / 4);          // 2176*512
    int i = blockIdx.x * 256 + threadIdx.x;
    if (i >= n4) return;
    int row = i >> 9;                      // / (2048/4)
    int c4  = i & 511;
    float4 v;
    if (row < 2048)      v = ((const float4*)Wdt)[(size_t)row * 512 + c4];
    else if (row < 2080) v = ((const float4*)Wx)[(size_t)(row - 2048) * 512 + c4];
    else                 v = make_float4(0.f, 0.f, 0.f, 0.f);
    ushort4 o;
    o.x = f2b(v.x); o.y = f2b(v.y); o.z = f2b(v.z); o.w = f2b(v.w);
    ((ushort4*)dst)[i] = o;
}

// ---------------------------------------------------------------------------
// bf16 MFMA GEMM: C[m,n] = sum_k A[m,k]*B[n,k], A: MxK, B: NxK, row-major.
// 128x128 tile, BK=64 (two 32-deep LDS half-stages, 32 MFMA per barrier),
// 4 waves (2x2), each wave 4x4 grid of 16x16x32 MFMA.
// 1D grid + GROUP_M=16 swizzle: 16 dispatch-adjacent blocks share one B-tile
// -> B re-fetched only npm/16 times from HBM (was ~every m-row).
// mode 0: bf16 split store  cols<2048 -> o0, else -> o1 (both ldc 2048)
// mode 1: cols<2048 -> softplus(v+bias[col]) fp32 o0 (ldc 2048);
//         2048..2063 -> o1[row*16+c]; 2064..2079 -> o2[row*16+c]; >=2080 drop
// mode 2: fp32 plain store to o0, ldc = N
// ---------------------------------------------------------------------------
__global__ __launch_bounds__(256)
void gemm_mfma(const unsigned short* __restrict__ A,
               const unsigned short* __restrict__ Bm,
               int M, int N, int K, int mode,
               const float* __restrict__ bias,
               void* __restrict__ o0, void* __restrict__ o1, void* __restrict__ o2)
{
    __shared__ unsigned short As[2][128 * 32];   // 2 x 8 KB (k-halves)
    __shared__ unsigned short Bs[2][128 * 32];   // 2 x 8 KB

    // GROUP_M swizzle (GM=16 divides npm=64 for all three GEMMs here)
    const int npn = N >> 7;
    const int pid = blockIdx.x;
    const int gsz = 16 * npn;
    const int gid = pid / gsz;
    const int pm  = gid * 16 + (pid % 16);
    const int pn  = (pid % gsz) / 16;
    const int bm  = pm * 128;
    const int bn  = pn * 128;

    const int tid  = threadIdx.x;
    const int lane = tid & 63;
    const int wave = tid >> 6;
    const int wm   = (wave >> 1) * 64;
    const int wn   = (wave & 1) * 64;

    f32x4 zero4 = {0.f, 0.f, 0.f, 0.f};
    f32x4 acc[4][4];
#pragma unroll
    for (int i = 0; i < 4; i++)
#pragma unroll
        for (int j = 0; j < 4; j++) acc[i][j] = zero4;

    // staging: thread -> 16B (8 bf16). row = tid/4 (0..63), col = (tid%4)*8
    const int sr = tid >> 2;
    const int sc = (tid & 3) * 8;
    const unsigned short* Ag = A  + (size_t)(bm + sr) * K + sc;
    const unsigned short* Bg = Bm + (size_t)(bn + sr) * K + sc;

    const int fr = lane & 15;          // row within 16-tile
    const int fk = (lane >> 4) * 8;    // k offset within 32

    for (int k0 = 0; k0 < K; k0 += 64) {
        // half 0: k0..k0+31, half 1: k0+32..k0+63
#pragma unroll
        for (int kh = 0; kh < 2; kh++) {
            const int ko = k0 + kh * 32;
            gld_lds16(Ag + ko,                  &As[kh][tid * 8]);
            gld_lds16(Ag + (size_t)64 * K + ko, &As[kh][2048 + tid * 8]);
            gld_lds16(Bg + ko,                  &Bs[kh][tid * 8]);
            gld_lds16(Bg + (size_t)64 * K + ko, &Bs[kh][2048 + tid * 8]);
        }
        __syncthreads();
#pragma unroll
        for (int kh = 0; kh < 2; kh++) {
            short8 af[4], bf[4];
#pragma unroll
            for (int i = 0; i < 4; i++) {
                af[i] = *(const short8*)&As[kh][(wm + i * 16 + fr) * 32 + fk];
                bf[i] = *(const short8*)&Bs[kh][(wn + i * 16 + fr) * 32 + fk];
            }
#pragma unroll
            for (int i = 0; i < 4; i++)
#pragma unroll
                for (int j = 0; j < 4; j++)
                    acc[i][j] = __builtin_amdgcn_mfma_f32_16x16x32_bf16(
                        af[i], bf[j], acc[i][j], 0, 0, 0);
        }
        __syncthreads();
    }

    // epilogue. C/D layout: col = lane&15, row = (lane>>4)*4 + r  [m89/m91]
    const int cr0 = bm + wm + (lane >> 4) * 4;
    const int cc0 = bn + wn + (lane & 15);
#pragma unroll
    for (int i = 0; i < 4; i++) {
#pragma unroll
        for (int j = 0; j < 4; j++) {
            const int col = cc0 + j * 16;
#pragma unroll
            for (int r = 0; r < 4; r++) {
                const int row = cr0 + i * 16 + r;
                float v = acc[i][j][r];
                if (mode == 0) {
                    if (col < 2048)
                        ((unsigned short*)o0)[(size_t)row * 2048 + col] = f2b(v);
                    else
                        ((unsigned short*)o1)[(size_t)row * 2048 + col - 2048] = f2b(v);
                } else if (mode == 1) {
                    if (col < 2048) {
                        ((float*)o0)[(size_t)row * 2048 + col] = softplusf(v + bias[col]);
                    } else if (col < 2064) {
                        ((float*)o1)[(size_t)row * DS + (col - 2048)] = v;
                    } else if (col < 2080) {
                        ((float*)o2)[(size_t)row * DS + (col - 2064)] = v;
                    }
                } else {
                    ((float*)o0)[(size_t)row * N + col] = v;
                }
            }
        }
    }
}

// ---------------------------------------------------------------------------
// Depthwise causal conv (width 4) + SiLU, bf16 in -> bf16 out.
// ---------------------------------------------------------------------------
__global__ __launch_bounds__(256)
void conv_silu(const unsigned short* __restrict__ xpb, const float* __restrict__ cw,
               const float* __restrict__ cb, unsigned short* __restrict__ xcb)
{
    const int idx = blockIdx.x * 256 + threadIdx.x;   // over BT*DI
    const int i  = idx & (DI - 1);
    const int bt = idx >> 11;
    const int t  = bt & (T_SZ - 1);
    float acc = cb[i];
    float4 w = *(const float4*)(cw + (size_t)i * 4);
    float wr[4] = {w.x, w.y, w.z, w.w};
#pragma unroll
    for (int k = 0; k < 4; k++) {
        const int tt = t - 3 + k;
        if (tt >= 0)
            acc = fmaf(b2f(xpb[(size_t)(bt - 3 + k) * DI + i]), wr[k], acc);
    }
    xcb[idx] = f2b(siluf(acc));
}

// ---------------------------------------------------------------------------
// Chunked parallel selective scan. Block: 16 chunks x 16 d-cols = 256 thr.
// Grid: (DI/16, B). Phase1: per-chunk (h_end, prod dA) from h0=0.
// Phase2: LDS carry combine. Phase3: replay with corrected h0, y in-place.
// ---------------------------------------------------------------------------
#define CH 16
#define CL (T_SZ / CH)   // 128

__global__ __launch_bounds__(256)
void scan2(const unsigned short* __restrict__ xcb, float* __restrict__ dty,
           const float* __restrict__ Bp, const float* __restrict__ Cp,
           const float* __restrict__ A_log)
{
    __shared__ float shH[CH][16][DS];
    __shared__ float shP[CH][16][DS];
    __shared__ float shI[CH][16][DS];
    const int tid = threadIdx.x;
    const int c = tid >> 4;
    const int g = tid & 15;
    const int b = blockIdx.y;
    const int d = blockIdx.x * 16 + g;

    float A[DS];
#pragma unroll
    for (int s = 0; s < DS; s++) A[s] = -__expf(A_log[s]);

    const size_t colbase = (size_t)b * T_SZ * DI + d;
    const unsigned short* xp = xcb + colbase + (size_t)c * CL * DI;
    float* dp = dty + colbase + (size_t)c * CL * DI;
    const float4* Bb = (const float4*)(Bp + ((size_t)b * T_SZ + c * CL) * DS);
    const float4* Cb = (const float4*)(Cp + ((size_t)b * T_SZ + c * CL) * DS);

    float h[DS], P[DS];
#pragma unroll
    for (int s = 0; s < DS; s++) { h[s] = 0.f; P[s] = 1.f; }

    for (int i = 0; i < CL; i++) {
        const float xv = b2f(xp[(size_t)i * DI]);
        const float dv = dp[(size_t)i * DI];
        float4 Bv[4] = {Bb[i*4+0], Bb[i*4+1], Bb[i*4+2], Bb[i*4+3]};
        const float* bs = (const float*)&Bv[0];
        const float dx = dv * xv;
#pragma unroll
        for (int s = 0; s < DS; s++) {
            const float dA = __expf(dv * A[s]);
            h[s] = fmaf(dA, h[s], dx * bs[s]);
            P[s] *= dA;
        }
    }
#pragma unroll
    for (int s = 0; s < DS; s += 4) {
        *(float4*)&shH[c][g][s] = make_float4(h[s], h[s+1], h[s+2], h[s+3]);
        *(float4*)&shP[c][g][s] = make_float4(P[s], P[s+1], P[s+2], P[s+3]);
    }
    __syncthreads();

    {
        const int g2 = tid >> 4, s2 = tid & 15;
        float hin = 0.f;
        shI[0][g2][s2] = 0.f;
        for (int cc = 1; cc < CH; cc++) {
            hin = fmaf(shP[cc-1][g2][s2], hin, shH[cc-1][g2][s2]);
            shI[cc][g2][s2] = hin;
        }
    }
    __syncthreads();

#pragma unroll
    for (int s = 0; s < DS; s++) h[s] = shI[c][g][s];
    for (int i = 0; i < CL; i++) {
        const float xv = b2f(xp[(size_t)i * DI]);
        const float dv = dp[(size_t)i * DI];
        float4 Bv[4] = {Bb[i*4+0], Bb[i*4+1], Bb[i*4+2], Bb[i*4+3]};
        float4 Cv[4] = {Cb[i*4+0], Cb[i*4+1], Cb[i*4+2], Cb[i*4+3]};
        const float* bs = (const float*)&Bv[0];
        const float* cs = (const float*)&Cv[0];
        const float dx = dv * xv;
        float yv = 0.f;
#pragma unroll
        for (int s = 0; s < DS; s++) {
            const float dA = __expf(dv * A[s]);
            h[s] = fmaf(dA, h[s], dx * bs[s]);
            yv = fmaf(h[s], cs[s], yv);
        }
        dp[(size_t)i * DI] = yv;   // overwrites dt[t] after its last use
    }
}

// ---------------------------------------------------------------------------
// Fused LayerNorm + xc*D residual + silu(z) gate. y fp32 in, yb bf16 out.
// ---------------------------------------------------------------------------
__global__ __launch_bounds__(256)
void ln_fuse(const float* __restrict__ y, const unsigned short* __restrict__ xcb,
             const unsigned short* __restrict__ zb, const float* __restrict__ g,
             const float* __restrict__ bln, const float* __restrict__ Dp,
             unsigned short* __restrict__ yb)
{
    __shared__ float rs[256], rss[256];
    const int bt  = blockIdx.x;
    const int tid = threadIdx.x;
    const float* yr = y + (size_t)bt * DI;
    const unsigned short* xr = xcb + (size_t)bt * DI;
    const unsigned short* zr = zb + (size_t)bt * DI;
    unsigned short* orow = yb + (size_t)bt * DI;

    float v[8];
    float s = 0.f, ss = 0.f;
#pragma unroll
    for (int j = 0; j < 8; j++) {
        v[j] = yr[tid + j * 256];
        s  += v[j];
        ss += v[j] * v[j];
    }
    rs[tid] = s; rss[tid] = ss;
    __syncthreads();
    for (int off = 128; off > 0; off >>= 1) {
        if (tid < off) { rs[tid] += rs[tid + off]; rss[tid] += rss[tid + off]; }
        __syncthreads();
    }
    const float mu   = rs[0] * (1.f / DI);
    const float var  = rss[0] * (1.f / DI) - mu * mu;
    const float rstd = rsqrtf(var + 1e-5f);
#pragma unroll
    for (int j = 0; j < 8; j++) {
        const int dcol = tid + j * 256;
        float yn = (v[j] - mu) * rstd * g[dcol] + bln[dcol];
        yn += b2f(xr[dcol]) * Dp[dcol];
        yn *= siluf(b2f(zr[dcol]));
        orow[dcol] = f2b(yn);
    }
}

// ---------------------------------------------------------------------------
// Workspace layout (MiB offsets, total ~175 MiB):
//   [  0, 32)  xpb bf16  (G1 out) -> dead after conv -> yb bf16 (ln out)
//   [ 32, 64)  zb  bf16
//   [ 64, 96)  xcb bf16
//   [ 96,160)  dts fp32 (G3 out) -> y fp32 (scan, in-place)
//       [ 96,112) xb bf16   (dead before G3 writes dts)
//       [112,120) W_inb bf16 (dead before G3)
//   [160,169)  Wcb bf16 (2176x2048: W_dt | W_x | zeros)
//   [169,173)  W_outb bf16
//   [174,175)  Bp, Cp fp32
// ---------------------------------------------------------------------------
extern "C" void kernel_launch(void* const* d_in, const int* in_sizes, int n_in,
                              void* d_out, int out_size, void* d_ws, size_t ws_size,
                              hipStream_t stream)
{
    const float* x      = (const float*)d_in[0];
    const float* W_in   = (const float*)d_in[1];
    const float* conv_w = (const float*)d_in[2];
    const float* conv_b = (const float*)d_in[3];
    const float* W_x    = (const float*)d_in[4];
    const float* W_dt   = (const float*)d_in[5];
    const float* b_dt   = (const float*)d_in[6];
    const float* A_log  = (const float*)d_in[7];
    const float* D_par  = (const float*)d_in[8];
    const float* W_out  = (const float*)d_in[9];
    const float* ln_g   = (const float*)d_in[10];
    const float* ln_b   = (const float*)d_in[11];
    float* out = (float*)d_out;

    char* w = (char*)d_ws;
    const size_t MB = 1ull << 20;
    unsigned short* xpb    = (unsigned short*)(w);
    unsigned short* zb     = (unsigned short*)(w + 32 * MB);
    unsigned short* xcb    = (unsigned short*)(w + 64 * MB);
    float*          dts    = (float*)(w + 96 * MB);
    unsigned short* xb     = (unsigned short*)(w + 96 * MB);
    unsigned short* W_inb  = (unsigned short*)(w + 112 * MB);
    unsigned short* Wcb    = (unsigned short*)(w + 160 * MB);
    unsigned short* W_outb = (unsigned short*)(w + 169 * MB);
    float*          BpF    = (float*)(w + 174 * MB);
    float*          CpF    = BpF + (size_t)BT * DS;
    unsigned short* yb     = xpb;   // reuse after conv

    dim3 blk(256);

    // conversions to bf16
    cvt_bf16<<<dim3((BT * DM / 4 + 255) / 256), blk, 0, stream>>>(x, xb, BT * DM / 4);
    cvt_bf16<<<dim3((2 * DI * DM / 4 + 255) / 256), blk, 0, stream>>>(W_in, W_inb, 2 * DI * DM / 4);
    cvt_wc<<<dim3((NC * DI / 4 + 255) / 256), blk, 0, stream>>>(W_dt, W_x, Wcb);
    cvt_bf16<<<dim3((DM * DI / 4 + 255) / 256), blk, 0, stream>>>(W_out, W_outb, DM * DI / 4);

    // 1) xz = x @ W_in^T -> split bf16 xpb | zb
    gemm_mfma<<<dim3((BT / 128) * (2 * DI / 128)), blk, 0, stream>>>(
        xb, W_inb, BT, 2 * DI, DM, 0, nullptr, xpb, zb, nullptr);

    // 2) depthwise conv + silu -> xcb bf16
    conv_silu<<<dim3(BT * DI / 256), blk, 0, stream>>>(xpb, conv_w, conv_b, xcb);

    // 3) fused dt+ssm GEMM: [W_dt | W_x] -> dts fp32 (softplus+bias), Bp, Cp
    gemm_mfma<<<dim3((BT / 128) * (NC / 128)), blk, 0, stream>>>(
        xcb, Wcb, BT, NC, DI, 1, b_dt, dts, BpF, CpF);

    // 4) chunked parallel scan -> y fp32 (in-place over dts)
    scan2<<<dim3(DI / 16, B_SZ), blk, 0, stream>>>(xcb, dts, BpF, CpF, A_log);

    // 5) LayerNorm + residual + gate -> yb bf16
    ln_fuse<<<dim3(BT), blk, 0, stream>>>(dts, xcb, zb, ln_g, ln_b, D_par, yb);

    // 6) out = y @ W_out^T -> fp32
    gemm_mfma<<<dim3((BT / 128) * (DM / 128)), blk, 0, stream>>>(
        yb, W_outb, BT, DM, DI, 2, nullptr, out, nullptr, nullptr);
}

// Round 5
// 633.116 us; speedup vs baseline: 5.9149x; 1.1646x over previous
//
#include <hip/hip_runtime.h>
#include <hip/hip_bf16.h>
#include <math.h>
#include <stdint.h>

// Problem constants (SelectiveSSM: D_MODEL=1024, D_STATE=16, D_CONV=4, EXPAND=2)
#define B_SZ 4
#define T_SZ 2048
#define DM   1024
#define DI   2048          // D_INNER
#define DS   16            // D_STATE
#define BT   (B_SZ*T_SZ)   // 8192
#define NC   2176          // padded N for fused dt+ssm GEMM (17 x 128)

typedef __attribute__((ext_vector_type(8))) short short8;
typedef __attribute__((ext_vector_type(4))) float f32x4;

__device__ __forceinline__ float siluf(float v) { return v / (1.f + __expf(-v)); }
__device__ __forceinline__ float softplusf(float x) {
    return fmaxf(x, 0.f) + log1pf(__expf(-fabsf(x)));
}
__device__ __forceinline__ unsigned short f2b(float f) {
    __hip_bfloat16 h = __float2bfloat16(f);
    return *reinterpret_cast<unsigned short*>(&h);
}
__device__ __forceinline__ float b2f(unsigned short u) {
    unsigned v = (unsigned)u << 16;
    float f;
    __builtin_memcpy(&f, &v, 4);
    return f;
}
__device__ __forceinline__ void gld_lds16(const void* g, void* l) {
    __builtin_amdgcn_global_load_lds(
        (const __attribute__((address_space(1))) unsigned int*)g,
        (__attribute__((address_space(3))) unsigned int*)l,
        16, 0, 0);
}

// ---------------------------------------------------------------------------
// fp32 -> bf16 conversion (vectorized x4)
// ---------------------------------------------------------------------------
__global__ __launch_bounds__(256)
void cvt_bf16(const float* __restrict__ src, unsigned short* __restrict__ dst, int n4)
{
    int i = blockIdx.x * 256 + threadIdx.x;
    if (i >= n4) return;
    float4 v = ((const float4*)src)[i];
    ushort4 o;
    o.x = f2b(v.x); o.y = f2b(v.y); o.z = f2b(v.z); o.w = f2b(v.w);
    ((ushort4*)dst)[i] = o;
}

// Pack W_dt (2048xK) + W_x (32xK) + zero pad into Wcb (2176xK) bf16
__global__ __launch_bounds__(256)
void cvt_wc(const float* __restrict__ Wdt, const float* __restrict__ Wx,
            unsigned short* __restrict__ dst)
{
    const int n4 = NC * (DI / 4);          // 2176*512
    int i = blockIdx.x * 256 + threadIdx.x;
    if (i >= n4) return;
    int row = i >> 9;                      // / (2048/4)
    int c4  = i & 511;
    float4 v;
    if (row < 2048)      v = ((const float4*)Wdt)[(size_t)row * 512 + c4];
    else if (row < 2080) v = ((const float4*)Wx)[(size_t)(row - 2048) * 512 + c4];
    else                 v = make_float4(0.f, 0.f, 0.f, 0.f);
    ushort4 o;
    o.x = f2b(v.x); o.y = f2b(v.y); o.z = f2b(v.z); o.w = f2b(v.w);
    ((ushort4*)dst)[i] = o;
}

// ---------------------------------------------------------------------------
// bf16 MFMA GEMM v3: C[m,n] = sum_k A[m,k]*B[n,k], A: MxK, B: NxK, row-major.
// 128x128 tile, 512 threads (8 waves, 2x4 grid, 64x32 wave-tile), BK=32,
// LDS DOUBLE-BUFFER with ONE barrier per K-iter: prefetch (global_load_lds)
// for iter k+1 issued BEFORE the MFMA phase of iter k, so the vmcnt(0) drain
// at the barrier is overlapped by compute. 64x32 wave-tile keeps regs ~100
// (acc 32 + frags 24) -> ~2x resident waves vs the 4-wave/64x64 version.
// 1D grid + GROUP_M=16 swizzle for B-tile L2 reuse.
// mode 0: bf16 split store  cols<2048 -> o0, else -> o1 (both ldc 2048)
// mode 1: cols<2048 -> softplus(v+bias[col]) fp32 o0 (ldc 2048);
//         2048..2063 -> o1[row*16+c]; 2064..2079 -> o2[row*16+c]; >=2080 drop
// mode 2: fp32 plain store to o0, ldc = N
// ---------------------------------------------------------------------------
__global__ __launch_bounds__(512)
void gemm_mfma(const unsigned short* __restrict__ A,
               const unsigned short* __restrict__ Bm,
               int M, int N, int K, int mode,
               const float* __restrict__ bias,
               void* __restrict__ o0, void* __restrict__ o1, void* __restrict__ o2)
{
    __shared__ unsigned short As[2][128 * 32];   // 2 x 8 KB
    __shared__ unsigned short Bs[2][128 * 32];   // 2 x 8 KB

    // GROUP_M swizzle (GM=16 divides npm=64 for all three GEMMs here)
    const int npn = N >> 7;
    const int pid = blockIdx.x;
    const int gsz = 16 * npn;
    const int gid = pid / gsz;
    const int pm  = gid * 16 + (pid % 16);
    const int pn  = (pid % gsz) / 16;
    const int bm  = pm * 128;
    const int bn  = pn * 128;

    const int tid  = threadIdx.x;
    const int lane = tid & 63;
    const int wave = tid >> 6;          // 0..7
    const int wm   = (wave >> 2) * 64;  // {0,64}
    const int wn   = (wave & 3) * 32;   // {0,32,64,96}

    f32x4 zero4 = {0.f, 0.f, 0.f, 0.f};
    f32x4 acc[4][2];
#pragma unroll
    for (int i = 0; i < 4; i++)
#pragma unroll
        for (int j = 0; j < 2; j++) acc[i][j] = zero4;

    // staging: 512 threads x 16B = one full 128x32 bf16 tile per matrix.
    // row = tid/4 (0..127), col = (tid%4)*8
    const int sr = tid >> 2;
    const int sc = (tid & 3) * 8;
    const unsigned short* Ag = A  + (size_t)(bm + sr) * K + sc;
    const unsigned short* Bg = Bm + (size_t)(bn + sr) * K + sc;

    const int fr = lane & 15;          // row within 16-tile
    const int fk = (lane >> 4) * 8;    // k offset within 32

    // prologue: stage k=0 into buf 0
    gld_lds16(Ag, &As[0][tid * 8]);
    gld_lds16(Bg, &Bs[0][tid * 8]);
    __syncthreads();

    int cur = 0;
    for (int k0 = 0; k0 < K; k0 += 32) {
        // prefetch next tile into the other buffer (async, drains at barrier)
        if (k0 + 32 < K) {
            gld_lds16(Ag + k0 + 32, &As[cur ^ 1][tid * 8]);
            gld_lds16(Bg + k0 + 32, &Bs[cur ^ 1][tid * 8]);
        }
        short8 af[4], bf[2];
#pragma unroll
        for (int i = 0; i < 4; i++)
            af[i] = *(const short8*)&As[cur][(wm + i * 16 + fr) * 32 + fk];
#pragma unroll
        for (int j = 0; j < 2; j++)
            bf[j] = *(const short8*)&Bs[cur][(wn + j * 16 + fr) * 32 + fk];
#pragma unroll
        for (int i = 0; i < 4; i++)
#pragma unroll
            for (int j = 0; j < 2; j++)
                acc[i][j] = __builtin_amdgcn_mfma_f32_16x16x32_bf16(
                    af[i], bf[j], acc[i][j], 0, 0, 0);
        __syncthreads();   // waits prefetch (vmcnt) + all reads of cur done
        cur ^= 1;
    }

    // epilogue. C/D layout: col = lane&15, row = (lane>>4)*4 + r  [m89/m91]
    const int cr0 = bm + wm + (lane >> 4) * 4;
    const int cc0 = bn + wn + (lane & 15);
#pragma unroll
    for (int i = 0; i < 4; i++) {
#pragma unroll
        for (int j = 0; j < 2; j++) {
            const int col = cc0 + j * 16;
#pragma unroll
            for (int r = 0; r < 4; r++) {
                const int row = cr0 + i * 16 + r;
                float v = acc[i][j][r];
                if (mode == 0) {
                    if (col < 2048)
                        ((unsigned short*)o0)[(size_t)row * 2048 + col] = f2b(v);
                    else
                        ((unsigned short*)o1)[(size_t)row * 2048 + col - 2048] = f2b(v);
                } else if (mode == 1) {
                    if (col < 2048) {
                        ((float*)o0)[(size_t)row * 2048 + col] = softplusf(v + bias[col]);
                    } else if (col < 2064) {
                        ((float*)o1)[(size_t)row * DS + (col - 2048)] = v;
                    } else if (col < 2080) {
                        ((float*)o2)[(size_t)row * DS + (col - 2064)] = v;
                    }
                } else {
                    ((float*)o0)[(size_t)row * N + col] = v;
                }
            }
        }
    }
}

// ---------------------------------------------------------------------------
// Depthwise causal conv (width 4) + SiLU, bf16 in -> bf16 out.
// ---------------------------------------------------------------------------
__global__ __launch_bounds__(256)
void conv_silu(const unsigned short* __restrict__ xpb, const float* __restrict__ cw,
               const float* __restrict__ cb, unsigned short* __restrict__ xcb)
{
    const int idx = blockIdx.x * 256 + threadIdx.x;   // over BT*DI
    const int i  = idx & (DI - 1);
    const int bt = idx >> 11;
    const int t  = bt & (T_SZ - 1);
    float acc = cb[i];
    float4 w = *(const float4*)(cw + (size_t)i * 4);
    float wr[4] = {w.x, w.y, w.z, w.w};
#pragma unroll
    for (int k = 0; k < 4; k++) {
        const int tt = t - 3 + k;
        if (tt >= 0)
            acc = fmaf(b2f(xpb[(size_t)(bt - 3 + k) * DI + i]), wr[k], acc);
    }
    xcb[idx] = f2b(siluf(acc));
}

// ---------------------------------------------------------------------------
// Chunked parallel selective scan. Block: 16 chunks x 16 d-cols = 256 thr.
// Grid: (DI/16, B). Phase1: per-chunk (h_end, prod dA) from h0=0.
// Phase2: LDS carry combine. Phase3: replay with corrected h0, y in-place.
// ---------------------------------------------------------------------------
#define CH 16
#define CL (T_SZ / CH)   // 128

__global__ __launch_bounds__(256)
void scan2(const unsigned short* __restrict__ xcb, float* __restrict__ dty,
           const float* __restrict__ Bp, const float* __restrict__ Cp,
           const float* __restrict__ A_log)
{
    __shared__ float shH[CH][16][DS];
    __shared__ float shP[CH][16][DS];
    __shared__ float shI[CH][16][DS];
    const int tid = threadIdx.x;
    const int c = tid >> 4;
    const int g = tid & 15;
    const int b = blockIdx.y;
    const int d = blockIdx.x * 16 + g;

    float A[DS];
#pragma unroll
    for (int s = 0; s < DS; s++) A[s] = -__expf(A_log[s]);

    const size_t colbase = (size_t)b * T_SZ * DI + d;
    const unsigned short* xp = xcb + colbase + (size_t)c * CL * DI;
    float* dp = dty + colbase + (size_t)c * CL * DI;
    const float4* Bb = (const float4*)(Bp + ((size_t)b * T_SZ + c * CL) * DS);
    const float4* Cb = (const float4*)(Cp + ((size_t)b * T_SZ + c * CL) * DS);

    float h[DS], P[DS];
#pragma unroll
    for (int s = 0; s < DS; s++) { h[s] = 0.f; P[s] = 1.f; }

    for (int i = 0; i < CL; i++) {
        const float xv = b2f(xp[(size_t)i * DI]);
        const float dv = dp[(size_t)i * DI];
        float4 Bv[4] = {Bb[i*4+0], Bb[i*4+1], Bb[i*4+2], Bb[i*4+3]};
        const float* bs = (const float*)&Bv[0];
        const float dx = dv * xv;
#pragma unroll
        for (int s = 0; s < DS; s++) {
            const float dA = __expf(dv * A[s]);
            h[s] = fmaf(dA, h[s], dx * bs[s]);
            P[s] *= dA;
        }
    }
#pragma unroll
    for (int s = 0; s < DS; s += 4) {
        *(float4*)&shH[c][g][s] = make_float4(h[s], h[s+1], h[s+2], h[s+3]);
        *(float4*)&shP[c][g][s] = make_float4(P[s], P[s+1], P[s+2], P[s+3]);
    }
    __syncthreads();

    {
        const int g2 = tid >> 4, s2 = tid & 15;
        float hin = 0.f;
        shI[0][g2][s2] = 0.f;
        for (int cc = 1; cc < CH; cc++) {
            hin = fmaf(shP[cc-1][g2][s2], hin, shH[cc-1][g2][s2]);
            shI[cc][g2][s2] = hin;
        }
    }
    __syncthreads();

#pragma unroll
    for (int s = 0; s < DS; s++) h[s] = shI[c][g][s];
    for (int i = 0; i < CL; i++) {
        const float xv = b2f(xp[(size_t)i * DI]);
        const float dv = dp[(size_t)i * DI];
        float4 Bv[4] = {Bb[i*4+0], Bb[i*4+1], Bb[i*4+2], Bb[i*4+3]};
        float4 Cv[4] = {Cb[i*4+0], Cb[i*4+1], Cb[i*4+2], Cb[i*4+3]};
        const float* bs = (const float*)&Bv[0];
        const float* cs = (const float*)&Cv[0];
        const float dx = dv * xv;
        float yv = 0.f;
#pragma unroll
        for (int s = 0; s < DS; s++) {
            const float dA = __expf(dv * A[s]);
            h[s] = fmaf(dA, h[s], dx * bs[s]);
            yv = fmaf(h[s], cs[s], yv);
        }
        dp[(size_t)i * DI] = yv;   // overwrites dt[t] after its last use
    }
}

// ---------------------------------------------------------------------------
// Fused LayerNorm + xc*D residual + silu(z) gate. y fp32 in, yb bf16 out.
// ---------------------------------------------------------------------------
__global__ __launch_bounds__(256)
void ln_fuse(const float* __restrict__ y, const unsigned short* __restrict__ xcb,
             const unsigned short* __restrict__ zb, const float* __restrict__ g,
             const float* __restrict__ bln, const float* __restrict__ Dp,
             unsigned short* __restrict__ yb)
{
    __shared__ float rs[256], rss[256];
    const int bt  = blockIdx.x;
    const int tid = threadIdx.x;
    const float* yr = y + (size_t)bt * DI;
    const unsigned short* xr = xcb + (size_t)bt * DI;
    const unsigned short* zr = zb + (size_t)bt * DI;
    unsigned short* orow = yb + (size_t)bt * DI;

    float v[8];
    float s = 0.f, ss = 0.f;
#pragma unroll
    for (int j = 0; j < 8; j++) {
        v[j] = yr[tid + j * 256];
        s  += v[j];
        ss += v[j] * v[j];
    }
    rs[tid] = s; rss[tid] = ss;
    __syncthreads();
    for (int off = 128; off > 0; off >>= 1) {
        if (tid < off) { rs[tid] += rs[tid + off]; rss[tid] += rss[tid + off]; }
        __syncthreads();
    }
    const float mu   = rs[0] * (1.f / DI);
    const float var  = rss[0] * (1.f / DI) - mu * mu;
    const float rstd = rsqrtf(var + 1e-5f);
#pragma unroll
    for (int j = 0; j < 8; j++) {
        const int dcol = tid + j * 256;
        float yn = (v[j] - mu) * rstd * g[dcol] + bln[dcol];
        yn += b2f(xr[dcol]) * Dp[dcol];
        yn *= siluf(b2f(zr[dcol]));
        orow[dcol] = f2b(yn);
    }
}

// ---------------------------------------------------------------------------
// Workspace layout (MiB offsets, total ~175 MiB):
//   [  0, 32)  xpb bf16  (G1 out) -> dead after conv -> yb bf16 (ln out)
//   [ 32, 64)  zb  bf16
//   [ 64, 96)  xcb bf16
//   [ 96,160)  dts fp32 (G3 out) -> y fp32 (scan, in-place)
//       [ 96,112) xb bf16   (dead before G3 writes dts)
//       [112,120) W_inb bf16 (dead before G3)
//   [160,169)  Wcb bf16 (2176x2048: W_dt | W_x | zeros)
//   [169,173)  W_outb bf16
//   [174,175)  Bp, Cp fp32
// ---------------------------------------------------------------------------
extern "C" void kernel_launch(void* const* d_in, const int* in_sizes, int n_in,
                              void* d_out, int out_size, void* d_ws, size_t ws_size,
                              hipStream_t stream)
{
    const float* x      = (const float*)d_in[0];
    const float* W_in   = (const float*)d_in[1];
    const float* conv_w = (const float*)d_in[2];
    const float* conv_b = (const float*)d_in[3];
    const float* W_x    = (const float*)d_in[4];
    const float* W_dt   = (const float*)d_in[5];
    const float* b_dt   = (const float*)d_in[6];
    const float* A_log  = (const float*)d_in[7];
    const float* D_par  = (const float*)d_in[8];
    const float* W_out  = (const float*)d_in[9];
    const float* ln_g   = (const float*)d_in[10];
    const float* ln_b   = (const float*)d_in[11];
    float* out = (float*)d_out;

    char* w = (char*)d_ws;
    const size_t MB = 1ull << 20;
    unsigned short* xpb    = (unsigned short*)(w);
    unsigned short* zb     = (unsigned short*)(w + 32 * MB);
    unsigned short* xcb    = (unsigned short*)(w + 64 * MB);
    float*          dts    = (float*)(w + 96 * MB);
    unsigned short* xb     = (unsigned short*)(w + 96 * MB);
    unsigned short* W_inb  = (unsigned short*)(w + 112 * MB);
    unsigned short* Wcb    = (unsigned short*)(w + 160 * MB);
    unsigned short* W_outb = (unsigned short*)(w + 169 * MB);
    float*          BpF    = (float*)(w + 174 * MB);
    float*          CpF    = BpF + (size_t)BT * DS;
    unsigned short* yb     = xpb;   // reuse after conv

    dim3 blk(256);
    dim3 blk512(512);

    // conversions to bf16
    cvt_bf16<<<dim3((BT * DM / 4 + 255) / 256), blk, 0, stream>>>(x, xb, BT * DM / 4);
    cvt_bf16<<<dim3((2 * DI * DM / 4 + 255) / 256), blk, 0, stream>>>(W_in, W_inb, 2 * DI * DM / 4);
    cvt_wc<<<dim3((NC * DI / 4 + 255) / 256), blk, 0, stream>>>(W_dt, W_x, Wcb);
    cvt_bf16<<<dim3((DM * DI / 4 + 255) / 256), blk, 0, stream>>>(W_out, W_outb, DM * DI / 4);

    // 1) xz = x @ W_in^T -> split bf16 xpb | zb
    gemm_mfma<<<dim3((BT / 128) * (2 * DI / 128)), blk512, 0, stream>>>(
        xb, W_inb, BT, 2 * DI, DM, 0, nullptr, xpb, zb, nullptr);

    // 2) depthwise conv + silu -> xcb bf16
    conv_silu<<<dim3(BT * DI / 256), blk, 0, stream>>>(xpb, conv_w, conv_b, xcb);

    // 3) fused dt+ssm GEMM: [W_dt | W_x] -> dts fp32 (softplus+bias), Bp, Cp
    gemm_mfma<<<dim3((BT / 128) * (NC / 128)), blk512, 0, stream>>>(
        xcb, Wcb, BT, NC, DI, 1, b_dt, dts, BpF, CpF);

    // 4) chunked parallel scan -> y fp32 (in-place over dts)
    scan2<<<dim3(DI / 16, B_SZ), blk, 0, stream>>>(xcb, dts, BpF, CpF, A_log);

    // 5) LayerNorm + residual + gate -> yb bf16
    ln_fuse<<<dim3(BT), blk, 0, stream>>>(dts, xcb, zb, ln_g, ln_b, D_par, yb);

    // 6) out = y @ W_out^T -> fp32
    gemm_mfma<<<dim3((BT / 128) * (DM / 128)), blk512, 0, stream>>>(
        yb, W_outb, BT, DM, DI, 2, nullptr, out, nullptr, nullptr);
}